// Round 5
// baseline (233.711 us; speedup 1.0000x reference)
//
#include <hip/hip_runtime.h>

typedef float f32x4 __attribute__((ext_vector_type(4)));

#define DIM 512
#define WPB 4                 // waves per block
#define BLOCK 256
#define GRID 2048             // 8192 waves = 32 waves/CU: fully persistent

// DPP cross-lane move (VALU pipe): 0xB1 xor1, 0x4E xor2, 0x141 half-mirror,
// 0x140 row-mirror. 4 stages + one ds_swizzle xor16 = 32-lane allreduce.
template <int CTRL>
__device__ __forceinline__ float dpp_mov(float x) {
    return __int_as_float(
        __builtin_amdgcn_update_dpp(0, __float_as_int(x), CTRL, 0xF, 0xF, true));
}
__device__ __forceinline__ float red32_add(float x) {
    x += dpp_mov<0xB1>(x);
    x += dpp_mov<0x4E>(x);
    x += dpp_mov<0x141>(x);
    x += dpp_mov<0x140>(x);
    x += __int_as_float(__builtin_amdgcn_ds_swizzle(__float_as_int(x), (16 << 10) | 0x1f));
    return x;
}
__device__ __forceinline__ float red32_max(float x) {
    x = fmaxf(x, dpp_mov<0xB1>(x));
    x = fmaxf(x, dpp_mov<0x4E>(x));
    x = fmaxf(x, dpp_mov<0x141>(x));
    x = fmaxf(x, dpp_mov<0x140>(x));
    x = fmaxf(x, __int_as_float(__builtin_amdgcn_ds_swizzle(__float_as_int(x), (16 << 10) | 0x1f)));
    return x;
}

// Persistent kernel, 2 rows per wave (lanes 0-31 / 32-63), 4 row-pairs per
// wave, register double-buffered: next pair's loads are in flight while the
// current pair computes, so VMEM streams like a copy kernel instead of the
// load-burst / compute / store-burst phase pattern of the die-per-row version.
__global__ __launch_bounds__(BLOCK) void sparsemax_kernel(
    const float* __restrict__ x, float* __restrict__ out, int batch) {
    const int wv   = threadIdx.x >> 6;
    const int lane = threadIdx.x & 63;
    const int half = lane >> 5;
    const int l    = lane & 31;
    const int nw   = gridDim.x * WPB;          // total waves (8192)
    const int npair = batch >> 1;

    int p = blockIdx.x * WPB + wv;             // this wave's first row-pair
    if (p >= npair) return;

    const f32x4* xp = reinterpret_cast<const f32x4*>(x);
    f32x4* op       = reinterpret_cast<f32x4*>(out);

    size_t ro = (size_t)(2 * p + half) * (DIM / 4) + l;
    f32x4 c0 = xp[ro], c1 = xp[ro + 32], c2 = xp[ro + 64], c3 = xp[ro + 96];

    while (true) {
        // ---- prefetch next pair (stays in flight through the compute) ----
        const int  pn   = p + nw;
        const bool more = pn < npair;
        f32x4 n0, n1, n2, n3;
        if (more) {
            const size_t rn = (size_t)(2 * pn + half) * (DIM / 4) + l;
            n0 = xp[rn]; n1 = xp[rn + 32]; n2 = xp[rn + 64]; n3 = xp[rn + 96];
        }

        // ---- compute current pair ----
        float z[16] = {c0.x, c0.y, c0.z, c0.w, c1.x, c1.y, c1.z, c1.w,
                       c2.x, c2.y, c2.z, c2.w, c3.x, c3.y, c3.z, c3.w};

        float m = z[0];
#pragma unroll
        for (int j = 1; j < 16; ++j) m = fmaxf(m, z[j]);
        m = red32_max(m);
        float tau = m - 1.0f;   // valid lower bound: p_max <= 1

        int kp0 = -1, kp1 = -1;
        for (int it = 0; it < 32; ++it) {
            float S = 0.f;
            int K0 = 0, K1 = 0;
#pragma unroll
            for (int j = 0; j < 16; ++j) {
                const bool in = z[j] > tau;
                const unsigned long long b = __ballot(in);
                K0 += __popc((unsigned)b);
                K1 += __popc((unsigned)(b >> 32));
                S += in ? z[j] : 0.f;
            }
            S = red32_add(S);
            if (K0 == kp0 && K1 == kp1) break;   // sets stable -> fixed point
            kp0 = K0; kp1 = K1;
            const float K = (float)(half ? K1 : K0);
            tau = (S - 1.0f) * __builtin_amdgcn_rcpf(K);   // K >= 1
        }

        f32x4 o[4];
#pragma unroll
        for (int j = 0; j < 16; ++j) o[j >> 2][j & 3] = fmaxf(0.f, z[j] - tau);
        __builtin_nontemporal_store(o[0], op + ro);
        __builtin_nontemporal_store(o[1], op + ro + 32);
        __builtin_nontemporal_store(o[2], op + ro + 64);
        __builtin_nontemporal_store(o[3], op + ro + 96);

        // ---- rotate double buffer ----
        if (!more) break;
        p  = pn;
        ro = (size_t)(2 * p + half) * (DIM / 4) + l;
        c0 = n0; c1 = n1; c2 = n2; c3 = n3;
    }
}

extern "C" void kernel_launch(void* const* d_in, const int* in_sizes, int n_in,
                              void* d_out, int out_size, void* d_ws, size_t ws_size,
                              hipStream_t stream) {
    const float* x = (const float*)d_in[0];
    float* out     = (float*)d_out;
    const int batch = in_sizes[0] / DIM;  // 65536
    sparsemax_kernel<<<GRID, BLOCK, 0, stream>>>(x, out, batch);
}